// Round 3
// baseline (18689.586 us; speedup 1.0000x reference)
//
#include <hip/hip_runtime.h>
#include <math.h>

#define B_ 64
#define G_ 640
#define D_ 256
#define H_ 8
#define DH_ 32
#define NBLK 4
#define GS 160            // G_/NBLK
#define NEG_INF_F (-1e9f)

__device__ __constant__ float INV_SQRT_DH = 0.17677669529663687f; // 1/sqrt(32)
__device__ __constant__ float INV_SQRT_D  = 0.0625f;              // 1/sqrt(256)

// ---------------------------------------------------------------------------
// K1: graph_embed (mean over G), fixed_ctx = ge @ W_fixed, q0 = fixed_ctx + ge @ W_step
// ---------------------------------------------------------------------------
__global__ __launch_bounds__(256) void precompute_ctx(
    const float* __restrict__ emb, const float* __restrict__ W_fixed,
    const float* __restrict__ W_step, float* __restrict__ fixed_ctx,
    float* __restrict__ q0)
{
  const int b = blockIdx.x, d = threadIdx.x;
  __shared__ float ge[D_];
  const float* eb = emb + (size_t)b * G_ * D_;
  float s = 0.f;
  for (int g = 0; g < G_; ++g) s += eb[(size_t)g * D_ + d];
  ge[d] = s * (1.0f / (float)G_);
  __syncthreads();
  float fc = 0.f, qq = 0.f;
  for (int k = 0; k < D_; ++k) {
    const float gk = ge[k];
    fc = fmaf(gk, W_fixed[k * D_ + d], fc);
    qq = fmaf(gk, W_step[k * D_ + d], qq);
  }
  fixed_ctx[b * D_ + d] = fc;
  q0[b * D_ + d] = fc + qq;
}

// ---------------------------------------------------------------------------
// K0: Bmat [256 x 1024] = [ gk | gv | Wc = W_node3 @ W_out^T | W_step ]
// ---------------------------------------------------------------------------
__global__ __launch_bounds__(256) void build_bmat(
    const float* __restrict__ W_node, const float* __restrict__ W_step,
    const float* __restrict__ W_out, float* __restrict__ Bmat)
{
  const int k = blockIdx.x, t = threadIdx.x;
  __shared__ float wn3[D_];
  wn3[t] = W_node[k * 768 + 512 + t];
  __syncthreads();
  Bmat[k * 1024 + t]       = W_node[k * 768 + t];
  Bmat[k * 1024 + 256 + t] = W_node[k * 768 + 256 + t];
  float acc = 0.f;
  for (int j = 0; j < D_; ++j) acc = fmaf(wn3[j], W_out[t * D_ + j], acc);
  Bmat[k * 1024 + 512 + t] = acc;
  Bmat[k * 1024 + 768 + t] = W_step[k * D_ + t];
}

// ---------------------------------------------------------------------------
// K2: C[40960 x 1024] = emb @ Bmat, scatter to gkT/gv/lk2T/q_all
// ---------------------------------------------------------------------------
__global__ __launch_bounds__(256) void gemm_scatter(
    const float* __restrict__ A, const float* __restrict__ Bm,
    const float* __restrict__ fixed_ctx,
    float* __restrict__ gkT, float* __restrict__ gv,
    float* __restrict__ lk2T, float* __restrict__ q_all)
{
  __shared__ float As[16][132];
  __shared__ float Bs[16][132];
  const int tid = threadIdx.x;
  const int bm = blockIdx.x;   // 320
  const int bn = blockIdx.y;   // 8
  const int tr = tid / 16, tc = tid % 16;
  const int row0 = bm * 128, col0 = bn * 128;
  float acc[8][8];
#pragma unroll
  for (int i = 0; i < 8; ++i)
#pragma unroll
    for (int j = 0; j < 8; ++j) acc[i][j] = 0.f;

  for (int k0 = 0; k0 < D_; k0 += 16) {
#pragma unroll
    for (int s = tid; s < 512; s += 256) {
      const int r = s >> 2, c4 = (s & 3) * 4;
      const float4 v = *(const float4*)&A[(size_t)(row0 + r) * D_ + k0 + c4];
      As[c4 + 0][r] = v.x; As[c4 + 1][r] = v.y;
      As[c4 + 2][r] = v.z; As[c4 + 3][r] = v.w;
    }
#pragma unroll
    for (int s = tid; s < 512; s += 256) {
      const int r = s >> 5, c4 = (s & 31) * 4;
      *(float4*)&Bs[r][c4] = *(const float4*)&Bm[(size_t)(k0 + r) * 1024 + col0 + c4];
    }
    __syncthreads();
#pragma unroll
    for (int kk = 0; kk < 16; ++kk) {
      float a[8], bfr[8];
#pragma unroll
      for (int i = 0; i < 8; ++i) a[i] = As[kk][tr * 8 + i];
#pragma unroll
      for (int j = 0; j < 8; ++j) bfr[j] = Bs[kk][tc * 8 + j];
#pragma unroll
      for (int i = 0; i < 8; ++i)
#pragma unroll
        for (int j = 0; j < 8; ++j) acc[i][j] = fmaf(a[i], bfr[j], acc[i][j]);
    }
    __syncthreads();
  }

#pragma unroll
  for (int i = 0; i < 8; ++i) {
    const int row = row0 + tr * 8 + i;
    const int bb = row / G_;
    const int g = row - bb * G_;
#pragma unroll
    for (int j = 0; j < 8; ++j) {
      const int n = col0 + tc * 8 + j;
      const float v = acc[i][j];
      if (n < 256) {
        const int h = n >> 5, d = n & 31;
        gkT[(((size_t)bb * H_ + h) * DH_ + d) * G_ + g] = v;
      } else if (n < 512) {
        const int m2 = n - 256, h = m2 >> 5, d = m2 & 31;
        gv[(((size_t)bb * H_ + h) * G_ + g) * DH_ + d] = v;
      } else if (n < 768) {
        const int d = n - 512;
        lk2T[((size_t)bb * D_ + d) * G_ + g] = v;
      } else {
        const int d = n - 768;
        q_all[((size_t)(bb * G_ + g)) * D_ + d] = v + fixed_ctx[bb * D_ + d];
      }
    }
  }
}

// ---------------------------------------------------------------------------
// K3: resident decode. 256 blocks (XCD-swizzled: 4 slices of one b share an
// XCD), 1024 threads, 1 block/CU. gk+gv live in regs+LDS for all 512 steps;
// only lk2 (163KB/slice) is streamed per step.
// ---------------------------------------------------------------------------
__global__ __launch_bounds__(1024) void step_resident(
    const float* __restrict__ gkT, const float* __restrict__ gv,
    const float* __restrict__ lk2T, const float* __restrict__ q_all,
    const float* __restrict__ q0, const int* __restrict__ n_steps_p,
    float* __restrict__ comm1, float* __restrict__ comm2,
    unsigned int* __restrict__ bar, float* __restrict__ out)
{
  // XCD swizzle: x = 32*bhi + 8*blk + xcd; b = bhi*8+xcd (same XCD for b's 4 slices)
  const int x   = blockIdx.x;
  const int b   = ((x >> 5) << 3) | (x & 7);
  const int blk = (x >> 3) & 3;
  const int t   = threadIdx.x;
  const int T   = *n_steps_p;
  const int g0  = blk * GS;
  float* out_logp = out;                          // [B][T][G]
  float* out_pi   = out + (size_t)B_ * T * G_;    // [B][T]

  // ---- LDS: 162,776 B total (<= 163,840) ----
  __shared__ float gv_lds[112 * H_ * DH_];   // [h][gl<112][d]  114,688 B
  __shared__ float gk_lds[256 * DH_];        // pairs 1024..1279  32,768 B
  __shared__ float attn_s[H_][GS];           // 5,120 B
  __shared__ float q_s[D_];                  // 1,024 B
  __shared__ float hpart[4][D_];             // 4,096 B
  __shared__ float hsum_part[4][H_];         // 128 B
  __shared__ float heads_s[D_];              // 1,024 B
  __shared__ float hsum_s[H_];               // 32 B
  __shared__ float logits_s[GS];             // 640 B
  __shared__ float lpart[4][GS];             // 2,560 B
  __shared__ int   vis[GS];                  // 640 B
  __shared__ float redv[4]; __shared__ int redi[4]; __shared__ float reds[4];
  __shared__ int   sel_s;
  __shared__ float lse_s;

  const int lane = t & 63;
  const int wave = t >> 6;
  const int r    = t & 3;        // d-quarter for phase 2
  const int base = t >> 2;       // pair base for phase 2
  const int part = t >> 8;       // 0..3 for phase 3
  const int hd   = t & 255;
  const int h3   = hd >> 5, d3 = hd & 31;

  // ---- one-time residency load ----
  float gk_r[4][8];              // pairs {k*256+base : k<4}, d = r*8..r*8+7
  int h_k[4], gl_k[4];
#pragma unroll
  for (int k = 0; k < 4; ++k) {
    const int p = k * 256 + base;
    const int h = p / 160, gl = p - h * 160;
    h_k[k] = h; gl_k[k] = gl;
    const float* src = gkT + (((size_t)b * H_ + h) * DH_ + r * 8) * G_ + g0 + gl;
#pragma unroll
    for (int j = 0; j < 8; ++j) gk_r[k][j] = src[(size_t)j * G_];
  }
  const int p4 = 1024 + base;
  const int h4 = p4 / 160, gl4 = p4 - h4 * 160;

  for (int idx = t; idx < 256 * DH_; idx += 1024) {
    const int pp = idx >> 5, d = idx & 31;
    const int p = 1024 + pp, h = p / 160, gl = p - h * 160;
    gk_lds[idx] = gkT[(((size_t)b * H_ + h) * DH_ + d) * G_ + g0 + gl];
  }
  for (int idx = t; idx < 112 * H_ * DH_; idx += 1024) {
    const int h = idx / 3584, rem = idx - h * 3584;   // rem = gl*32+d
    gv_lds[idx] = gv[(((size_t)b * H_ + h) * G_ + g0) * DH_ + rem];
  }
  float gv_r[12];                // gl = 112 + part*12 + i, (h3,d3)
  {
    const float* src = gv + (((size_t)b * H_ + h3) * G_ + g0 + 112 + part * 12) * DH_ + d3;
#pragma unroll
    for (int i = 0; i < 12; ++i) gv_r[i] = src[(size_t)i * DH_];
  }

  for (int i = t; i < GS; i += 1024) vis[i] = 0;
  if (t == 0) sel_s = 0;
  __syncthreads();

  unsigned int* mybar = bar + b * 32;
  float* c1 = comm1 + (size_t)b * NBLK * 264;
  float* c2 = comm2 + (size_t)b * NBLK * 4;

  for (int step = 0; step < T; ++step) {
    // ---- phase 1: q ----
    const float* qsrc = (step == 0) ? (q0 + (size_t)b * D_)
                                    : (q_all + ((size_t)b * G_ + sel_s) * D_);
    if (t < D_) q_s[t] = qsrc[t];
    __syncthreads();

    // ---- phase 2: e[h][gl] = exp(compat), masked -> 0 (resident gk) ----
#pragma unroll
    for (int k = 0; k < 4; ++k) {
      float acc = 0.f;
#pragma unroll
      for (int j = 0; j < 8; ++j)
        acc = fmaf(q_s[h_k[k] * DH_ + r * 8 + j], gk_r[k][j], acc);
      acc += __shfl_xor(acc, 1);
      acc += __shfl_xor(acc, 2);
      if (r == 0)
        attn_s[h_k[k]][gl_k[k]] = vis[gl_k[k]] ? 0.f : expf(acc * INV_SQRT_DH);
    }
    {
      const float4 ga = *(const float4*)&gk_lds[base * DH_ + r * 8];
      const float4 gb = *(const float4*)&gk_lds[base * DH_ + r * 8 + 4];
      const float* qh = &q_s[h4 * DH_ + r * 8];
      float acc = qh[0] * ga.x;
      acc = fmaf(qh[1], ga.y, acc); acc = fmaf(qh[2], ga.z, acc);
      acc = fmaf(qh[3], ga.w, acc); acc = fmaf(qh[4], gb.x, acc);
      acc = fmaf(qh[5], gb.y, acc); acc = fmaf(qh[6], gb.z, acc);
      acc = fmaf(qh[7], gb.w, acc);
      acc += __shfl_xor(acc, 1);
      acc += __shfl_xor(acc, 2);
      if (r == 0)
        attn_s[h4][gl4] = vis[gl4] ? 0.f : expf(acc * INV_SQRT_DH);
    }
    __syncthreads();

    // ---- phase 3: partial heads (resident gv) ----
    {
      const float* gvl = &gv_lds[(h3 * 112 + part * 28) * DH_ + d3];
      const float* arow = attn_s[h3];
      float p = 0.f, se = 0.f;
#pragma unroll
      for (int i = 0; i < 28; ++i) {
        const float e = arow[part * 28 + i];
        p = fmaf(e, gvl[i * DH_], p);
        se += e;
      }
#pragma unroll
      for (int i = 0; i < 12; ++i) {
        const float e = arow[112 + part * 12 + i];
        p = fmaf(e, gv_r[i], p);
        se += e;
      }
      hpart[part][hd] = p;
      if (d3 == 0) hsum_part[part][h3] = se;
    }
    __syncthreads();
    if (t < 256) {
      const float s = hpart[0][t] + hpart[1][t] + hpart[2][t] + hpart[3][t];
      __hip_atomic_store(&c1[blk * 264 + t], s, __ATOMIC_RELAXED, __HIP_MEMORY_SCOPE_AGENT);
    } else if (t < 264) {
      const int h = t - 256;
      const float s = hsum_part[0][h] + hsum_part[1][h] + hsum_part[2][h] + hsum_part[3][h];
      __hip_atomic_store(&c1[blk * 264 + t], s, __ATOMIC_RELAXED, __HIP_MEMORY_SCOPE_AGENT);
    }
    __syncthreads();
    if (t == 0) {
      __hip_atomic_fetch_add(mybar, 1u, __ATOMIC_RELEASE, __HIP_MEMORY_SCOPE_AGENT);
      const unsigned tgt = (unsigned)step * 8u + 4u;
      while (__hip_atomic_load(mybar, __ATOMIC_ACQUIRE, __HIP_MEMORY_SCOPE_AGENT) < tgt)
        __builtin_amdgcn_s_sleep(2);
    }
    __syncthreads();

    // ---- combine heads across 4 blocks ----
    float hval = 0.f;
    if (t < 256) {
#pragma unroll
      for (int k = 0; k < NBLK; ++k)
        hval += __hip_atomic_load(&c1[k * 264 + t], __ATOMIC_RELAXED, __HIP_MEMORY_SCOPE_AGENT);
    } else if (t < 264) {
      float s = 0.f;
#pragma unroll
      for (int k = 0; k < NBLK; ++k)
        s += __hip_atomic_load(&c1[k * 264 + t], __ATOMIC_RELAXED, __HIP_MEMORY_SCOPE_AGENT);
      hsum_s[t - 256] = s;
    }
    __syncthreads();
    if (t < 256) heads_s[t] = hval / hsum_s[t >> 5];
    __syncthreads();

    // ---- phase 4: logits (stream lk2T slice) ----
    if (t < 640) {
      const int p4a = t / 160;
      const int gl = t - p4a * 160;
      const float* lkb = lk2T + ((size_t)b * D_ + p4a * 64) * G_ + (g0 + gl);
      const float* hh = &heads_s[p4a * 64];
      float a0 = 0.f;
#pragma unroll 16
      for (int d = 0; d < 64; ++d) a0 = fmaf(hh[d], lkb[(size_t)d * G_], a0);
      lpart[p4a][gl] = a0;
    }
    __syncthreads();

    float lval = -INFINITY, eval = 0.f;
    int gidx = 1 << 30;
    if (t < GS) {
      const float a = (lpart[0][t] + lpart[1][t] + lpart[2][t] + lpart[3][t]) * INV_SQRT_D;
      float lg = 10.0f * tanhf(a);
      if (vis[t]) lg = NEG_INF_F;
      logits_s[t] = lg;
      lval = lg; gidx = g0 + t;
      eval = expf(lg - 10.0f);
    }
    if (t < 192) {
      float v = lval; int vi = gidx; float es = eval;
#pragma unroll
      for (int off = 32; off; off >>= 1) {
        const float ov = __shfl_down(v, off);
        const int oi = __shfl_down(vi, off);
        const float oe = __shfl_down(es, off);
        es += oe;
        if (ov > v || (ov == v && oi < vi)) { v = ov; vi = oi; }
      }
      if (lane == 0) { redv[wave] = v; redi[wave] = vi; reds[wave] = es; }
    }
    __syncthreads();
    if (t == 0) {
      float mv = redv[0]; int mi = redi[0]; float ss = reds[0];
      for (int w = 1; w < 3; ++w) {
        ss += reds[w];
        if (redv[w] > mv || (redv[w] == mv && redi[w] < mi)) { mv = redv[w]; mi = redi[w]; }
      }
      __hip_atomic_store(&c2[blk * 4 + 0], mv, __ATOMIC_RELAXED, __HIP_MEMORY_SCOPE_AGENT);
      __hip_atomic_store(&c2[blk * 4 + 1], __int_as_float(mi), __ATOMIC_RELAXED, __HIP_MEMORY_SCOPE_AGENT);
      __hip_atomic_store(&c2[blk * 4 + 2], ss, __ATOMIC_RELAXED, __HIP_MEMORY_SCOPE_AGENT);
    }
    __syncthreads();
    if (t == 0) {
      __hip_atomic_fetch_add(mybar, 1u, __ATOMIC_RELEASE, __HIP_MEMORY_SCOPE_AGENT);
      const unsigned tgt = (unsigned)step * 8u + 8u;
      while (__hip_atomic_load(mybar, __ATOMIC_ACQUIRE, __HIP_MEMORY_SCOPE_AGENT) < tgt)
        __builtin_amdgcn_s_sleep(2);
      float mv = -INFINITY; int mi = 1 << 30; float ss = 0.f;
#pragma unroll
      for (int k = 0; k < NBLK; ++k) {
        const float v = __hip_atomic_load(&c2[k * 4 + 0], __ATOMIC_RELAXED, __HIP_MEMORY_SCOPE_AGENT);
        const int vi = __float_as_int(__hip_atomic_load(&c2[k * 4 + 1], __ATOMIC_RELAXED, __HIP_MEMORY_SCOPE_AGENT));
        ss += __hip_atomic_load(&c2[k * 4 + 2], __ATOMIC_RELAXED, __HIP_MEMORY_SCOPE_AGENT);
        if (v > mv || (v == mv && vi < mi)) { mv = v; mi = vi; }
      }
      sel_s = mi;
      lse_s = 10.0f + logf(ss);
      if (mi >= g0 && mi < g0 + GS) vis[mi - g0] = 1;
      if (blk == 0) out_pi[(size_t)b * T + step] = (float)mi;
    }
    __syncthreads();

    if (t < GS) out_logp[((size_t)b * T + step) * G_ + (g0 + t)] = logits_s[t] - lse_s;
  }
}

// ---------------------------------------------------------------------------
extern "C" void kernel_launch(void* const* d_in, const int* in_sizes, int n_in,
                              void* d_out, int out_size, void* d_ws, size_t ws_size,
                              hipStream_t stream)
{
  const float* emb     = (const float*)d_in[0];
  const float* W_node  = (const float*)d_in[1];
  const float* W_fixed = (const float*)d_in[2];
  const float* W_step  = (const float*)d_in[3];
  const float* W_out   = (const float*)d_in[4];
  const int*   n_steps = (const int*)d_in[5];

  float* ws = (float*)d_ws;
  float* fixed_ctx = ws;
  float* q0        = fixed_ctx + B_ * D_;
  float* Bmat      = q0 + B_ * D_;
  float* gkT       = Bmat + D_ * 1024;
  float* gv        = gkT + (size_t)B_ * D_ * G_;
  float* lk2T      = gv + (size_t)B_ * D_ * G_;
  float* q_all     = lk2T + (size_t)B_ * D_ * G_;
  float* comm1     = q_all + (size_t)B_ * G_ * D_;
  float* comm2     = comm1 + (size_t)B_ * NBLK * 264;
  unsigned int* bar = (unsigned int*)(comm2 + (size_t)B_ * NBLK * 4);

  hipMemsetAsync(bar, 0, B_ * 32 * sizeof(unsigned int), stream);
  precompute_ctx<<<B_, 256, 0, stream>>>(emb, W_fixed, W_step, fixed_ctx, q0);
  build_bmat<<<D_, 256, 0, stream>>>(W_node, W_step, W_out, Bmat);
  gemm_scatter<<<dim3(320, 8), 256, 0, stream>>>(emb, Bmat, fixed_ctx,
                                                 gkT, gv, lk2T, q_all);
  step_resident<<<B_ * NBLK, 1024, 0, stream>>>(gkT, gv, lk2T, q_all, q0, n_steps,
                                                comm1, comm2, bar, (float*)d_out);
}

// Round 4
// 7271.372 us; speedup vs baseline: 2.5703x; 2.5703x over previous
//
#include <hip/hip_runtime.h>
#include <math.h>

#define B_ 64
#define G_ 640
#define D_ 256
#define H_ 8
#define DH_ 32
#define NBLK 4
#define TPB 512
#define GVL 512           // g's of gv kept in LDS (rest in regs)
#define GVSTR 516         // padded LDS row stride (floats): 516%32=4 -> bank-tiled, 16B-aligned
#define NEG_INF_F (-1e9f)

__device__ __constant__ float INV_SQRT_DH = 0.17677669529663687f; // 1/sqrt(32)
__device__ __constant__ float INV_SQRT_D  = 0.0625f;              // 1/sqrt(256)

// ---------------------------------------------------------------------------
// K1: graph_embed (mean over G), fixed_ctx = ge @ W_fixed, q0 = fixed_ctx + ge @ W_step
// ---------------------------------------------------------------------------
__global__ __launch_bounds__(256) void precompute_ctx(
    const float* __restrict__ emb, const float* __restrict__ W_fixed,
    const float* __restrict__ W_step, float* __restrict__ fixed_ctx,
    float* __restrict__ q0)
{
  const int b = blockIdx.x, d = threadIdx.x;
  __shared__ float ge[D_];
  const float* eb = emb + (size_t)b * G_ * D_;
  float s = 0.f;
  for (int g = 0; g < G_; ++g) s += eb[(size_t)g * D_ + d];
  ge[d] = s * (1.0f / (float)G_);
  __syncthreads();
  float fc = 0.f, qq = 0.f;
  for (int k = 0; k < D_; ++k) {
    const float gk = ge[k];
    fc = fmaf(gk, W_fixed[k * D_ + d], fc);
    qq = fmaf(gk, W_step[k * D_ + d], qq);
  }
  fixed_ctx[b * D_ + d] = fc;
  q0[b * D_ + d] = fc + qq;
}

// ---------------------------------------------------------------------------
// K0: Bmat [256 x 1024] = [ gk | gv | Wc = W_node3 @ W_out^T | W_step ]
// ---------------------------------------------------------------------------
__global__ __launch_bounds__(256) void build_bmat(
    const float* __restrict__ W_node, const float* __restrict__ W_step,
    const float* __restrict__ W_out, float* __restrict__ Bmat)
{
  const int k = blockIdx.x, t = threadIdx.x;
  __shared__ float wn3[D_];
  wn3[t] = W_node[k * 768 + 512 + t];
  __syncthreads();
  Bmat[k * 1024 + t]       = W_node[k * 768 + t];
  Bmat[k * 1024 + 256 + t] = W_node[k * 768 + 256 + t];
  float acc = 0.f;
  for (int j = 0; j < D_; ++j) acc = fmaf(wn3[j], W_out[t * D_ + j], acc);
  Bmat[k * 1024 + 512 + t] = acc;
  Bmat[k * 1024 + 768 + t] = W_step[k * D_ + t];
}

// ---------------------------------------------------------------------------
// K2: C[40960 x 1024] = emb @ Bmat, scatter to gkT/gv/lk2T/q_all
// ---------------------------------------------------------------------------
__global__ __launch_bounds__(256) void gemm_scatter(
    const float* __restrict__ A, const float* __restrict__ Bm,
    const float* __restrict__ fixed_ctx,
    float* __restrict__ gkT, float* __restrict__ gv,
    float* __restrict__ lk2T, float* __restrict__ q_all)
{
  __shared__ float As[16][132];
  __shared__ float Bs[16][132];
  const int tid = threadIdx.x;
  const int bm = blockIdx.x;   // 320
  const int bn = blockIdx.y;   // 8
  const int tr = tid / 16, tc = tid % 16;
  const int row0 = bm * 128, col0 = bn * 128;
  float acc[8][8];
#pragma unroll
  for (int i = 0; i < 8; ++i)
#pragma unroll
    for (int j = 0; j < 8; ++j) acc[i][j] = 0.f;

  for (int k0 = 0; k0 < D_; k0 += 16) {
#pragma unroll
    for (int s = tid; s < 512; s += 256) {
      const int r = s >> 2, c4 = (s & 3) * 4;
      const float4 v = *(const float4*)&A[(size_t)(row0 + r) * D_ + k0 + c4];
      As[c4 + 0][r] = v.x; As[c4 + 1][r] = v.y;
      As[c4 + 2][r] = v.z; As[c4 + 3][r] = v.w;
    }
#pragma unroll
    for (int s = tid; s < 512; s += 256) {
      const int r = s >> 5, c4 = (s & 31) * 4;
      *(float4*)&Bs[r][c4] = *(const float4*)&Bm[(size_t)(k0 + r) * 1024 + col0 + c4];
    }
    __syncthreads();
#pragma unroll
    for (int kk = 0; kk < 16; ++kk) {
      float a[8], bfr[8];
#pragma unroll
      for (int i = 0; i < 8; ++i) a[i] = As[kk][tr * 8 + i];
#pragma unroll
      for (int j = 0; j < 8; ++j) bfr[j] = Bs[kk][tc * 8 + j];
#pragma unroll
      for (int i = 0; i < 8; ++i)
#pragma unroll
        for (int j = 0; j < 8; ++j) acc[i][j] = fmaf(a[i], bfr[j], acc[i][j]);
    }
    __syncthreads();
  }

#pragma unroll
  for (int i = 0; i < 8; ++i) {
    const int row = row0 + tr * 8 + i;
    const int bb = row / G_;
    const int g = row - bb * G_;
#pragma unroll
    for (int j = 0; j < 8; ++j) {
      const int n = col0 + tc * 8 + j;
      const float v = acc[i][j];
      if (n < 256) {
        const int h = n >> 5, d = n & 31;
        gkT[(((size_t)bb * H_ + h) * DH_ + d) * G_ + g] = v;
      } else if (n < 512) {
        const int m2 = n - 256, h = m2 >> 5, d = m2 & 31;
        gv[(((size_t)bb * H_ + h) * G_ + g) * DH_ + d] = v;
      } else if (n < 768) {
        const int d = n - 512;
        lk2T[((size_t)bb * D_ + d) * G_ + g] = v;
      } else {
        const int d = n - 768;
        q_all[((size_t)(bb * G_ + g)) * D_ + d] = v + fixed_ctx[bb * D_ + d];
      }
    }
  }
}

// ---------------------------------------------------------------------------
// K3: head-split resident decode. 256 blocks = 64 b x 4, 512 threads.
// Block blk owns heads {2blk,2blk+1} (all 640 g) == heads-vector d-range
// [64*blk, 64*blk+64). gk/lk2 in regs, gv in LDS+regs. One barrier/step.
// ---------------------------------------------------------------------------
__global__ __launch_bounds__(TPB, 2) void step_headsplit(
    const float* __restrict__ gkT, const float* __restrict__ gv,
    const float* __restrict__ lk2T, const float* __restrict__ q_all,
    const float* __restrict__ q0, const int* __restrict__ n_steps_p,
    float* __restrict__ comm1, unsigned int* __restrict__ bar,
    float* __restrict__ out)
{
  const int x = blockIdx.x;
  const int b   = ((x >> 5) << 3) | (x & 7);   // XCD-swizzle heuristic
  const int blk = (x >> 3) & 3;
  const int t = threadIdx.x;
  const int T = *n_steps_p;
  const int h0 = blk * 2;
  const int d0 = blk * 64;
  float* out_logp = out;                         // [B][T][G]
  float* out_pi   = out + (size_t)B_ * T * G_;   // [B][T]

  // ---- LDS: ~148 KB ----
  __shared__ __align__(16) float gv_lds[2 * DH_ * GVSTR];  // [hh][d][g<512] 132,096 B
  __shared__ __align__(16) float attn_s[2 * G_];           // 5,120 B
  __shared__ __align__(16) float plog_l[G_];               // 2,560 B
  __shared__ float logits_s[G_];                           // 2,560 B
  __shared__ int   vis[G_];                                // 2,560 B
  __shared__ float hpart[8][64];                           // 2,048 B
  __shared__ float esum_p[8][2];
  __shared__ float heads_s[64];
  __shared__ float q_s[64];
  __shared__ float redv[8]; __shared__ int redi[8]; __shared__ float reds[8];
  __shared__ int   sel_s;
  __shared__ float lse_s;

  const int lane = t & 63, wave = t >> 6;
  const int qt  = t & 3;        // phase-2 d-quarter
  const int oct = t & 7;        // phase-4 d-octet
  const int part3 = t >> 6;     // phase-3 g-part (== wave)
  const int hd3 = t & 63;
  const int hh3 = hd3 >> 5, dd3 = hd3 & 31;

  // ---- one-time residency loads ----
  float gk_r[10][8];            // (h,g) pair p = k*128 + t/4; quarter qt
#pragma unroll
  for (int k = 0; k < 10; ++k) {
    const int p = k * 128 + (t >> 2);
    const int hh = (p >= G_) ? 1 : 0;
    const int g = p - hh * G_;
    const float* src = gkT + (((size_t)b * H_ + h0 + hh) * DH_ + qt * 8) * G_ + g;
#pragma unroll
    for (int j = 0; j < 8; ++j) gk_r[k][j] = src[(size_t)j * G_];
  }
  float lk_r[10][8];            // g = k*64 + t/8; octet oct
#pragma unroll
  for (int k = 0; k < 10; ++k) {
    const int g = k * 64 + (t >> 3);
    const float* src = lk2T + ((size_t)b * D_ + d0 + oct * 8) * G_ + g;
#pragma unroll
    for (int j = 0; j < 8; ++j) lk_r[k][j] = src[(size_t)j * G_];
  }
  for (int idx = t; idx < 2 * GVL * DH_; idx += TPB) {   // coalesced in d
    const int d = idx & 31, g = (idx >> 5) & (GVL - 1), hh = idx >> 14;
    gv_lds[(hh * DH_ + d) * GVSTR + g] =
        gv[(((size_t)b * H_ + h0 + hh) * G_ + g) * DH_ + d];
  }
  float gv_r[16];               // g in [512,640): g = 512 + part3*16 + i, (hh3,dd3)
  {
    const float* src = gv + (((size_t)b * H_ + h0 + hh3) * G_ + GVL + part3 * 16) * DH_ + dd3;
#pragma unroll
    for (int i = 0; i < 16; ++i) gv_r[i] = src[(size_t)i * DH_];
  }

  for (int idx = t; idx < G_; idx += TPB) vis[idx] = 0;
  if (t == 0) sel_s = 0;
  __syncthreads();

  unsigned int* mybar = bar + b * 32;

  for (int step = 0; step < T; ++step) {
    // ---- phase 1: q slice (only this block's 64 components) ----
    const float* qsrc = (step == 0) ? (q0 + (size_t)b * D_)
                                    : (q_all + ((size_t)b * G_ + sel_s) * D_);
    if (t < 64) q_s[t] = qsrc[d0 + t];
    __syncthreads();

    // ---- phase 2: e[hh][g] = exp(qk/sqrt(dh)), masked -> 0 ----
    float qreg[2][8];
#pragma unroll
    for (int hh = 0; hh < 2; ++hh)
#pragma unroll
      for (int j = 0; j < 8; ++j) qreg[hh][j] = q_s[hh * 32 + qt * 8 + j];
#pragma unroll
    for (int k = 0; k < 10; ++k) {
      const int p = k * 128 + (t >> 2);
      const int hh = (p >= G_) ? 1 : 0;
      const int g = p - hh * G_;
      float a = 0.f;
#pragma unroll
      for (int j = 0; j < 8; ++j) a = fmaf(qreg[hh][j], gk_r[k][j], a);
      a += __shfl_xor(a, 1);
      a += __shfl_xor(a, 2);
      if (qt == 0) attn_s[hh * G_ + g] = vis[g] ? 0.f : expf(a * INV_SQRT_DH);
    }
    __syncthreads();

    // ---- phase 3: local heads[64] = sum_g e*gv (8 g-parts) ----
    {
      const float* gvrow = &gv_lds[(hh3 * DH_ + dd3) * GVSTR];
      const float* arow = &attn_s[hh3 * G_];
      float acc = 0.f, es = 0.f;
      const int gA = part3 * 64;
#pragma unroll
      for (int i = 0; i < 16; ++i) {
        const float4 ev = *(const float4*)&arow[gA + i * 4];
        const float4 gvv = *(const float4*)&gvrow[gA + i * 4];
        acc = fmaf(ev.x, gvv.x, acc); acc = fmaf(ev.y, gvv.y, acc);
        acc = fmaf(ev.z, gvv.z, acc); acc = fmaf(ev.w, gvv.w, acc);
        if (dd3 == 0) es += ev.x + ev.y + ev.z + ev.w;
      }
      const int gB = GVL + part3 * 16;
#pragma unroll
      for (int i = 0; i < 16; ++i) {
        const float e = arow[gB + i];
        acc = fmaf(e, gv_r[i], acc);
        if (dd3 == 0) es += e;
      }
      hpart[part3][hd3] = acc;
      if (dd3 == 0) esum_p[part3][hh3] = es;
    }
    __syncthreads();
    if (t < 64) {
      float num = 0.f, den = 0.f;
#pragma unroll
      for (int p = 0; p < 8; ++p) num += hpart[p][t];
#pragma unroll
      for (int p = 0; p < 8; ++p) den += esum_p[p][t >> 5];
      heads_s[t] = num / den;
    }
    __syncthreads();

    // ---- phase 4: partial logits over local 64 d's, all g ----
    float hreg[8];
#pragma unroll
    for (int j = 0; j < 8; ++j) hreg[j] = heads_s[oct * 8 + j];
#pragma unroll
    for (int k = 0; k < 10; ++k) {
      float a = 0.f;
#pragma unroll
      for (int j = 0; j < 8; ++j) a = fmaf(hreg[j], lk_r[k][j], a);
      a += __shfl_xor(a, 1);
      a += __shfl_xor(a, 2);
      a += __shfl_xor(a, 4);
      if (oct == 0) plog_l[k * 64 + (t >> 3)] = a;
    }
    __syncthreads();

    // ---- publish partials + single barrier round ----
    float* myslot = comm1 + (((size_t)b * 2 + (step & 1)) * NBLK + blk) * G_;
    for (int idx = t; idx < G_; idx += TPB)
      __hip_atomic_store(&myslot[idx], plog_l[idx], __ATOMIC_RELAXED, __HIP_MEMORY_SCOPE_AGENT);
    __syncthreads();
    if (t == 0) {
      __hip_atomic_fetch_add(mybar, 1u, __ATOMIC_RELEASE, __HIP_MEMORY_SCOPE_AGENT);
      const unsigned tgt = (unsigned)(step + 1) * NBLK;
      while (__hip_atomic_load(mybar, __ATOMIC_ACQUIRE, __HIP_MEMORY_SCOPE_AGENT) < tgt)
        __builtin_amdgcn_s_sleep(2);
    }
    __syncthreads();

    // ---- combine (identical order in all blocks -> bit-identical logits) ----
    const float* cbase = comm1 + ((size_t)b * 2 + (step & 1)) * NBLK * G_;
    for (int idx = t; idx < G_; idx += TPB) {
      float s = 0.f;
#pragma unroll
      for (int kk = 0; kk < NBLK; ++kk)
        s += __hip_atomic_load(&cbase[kk * G_ + idx], __ATOMIC_RELAXED, __HIP_MEMORY_SCOPE_AGENT);
      float lg = 10.0f * tanhf(s * INV_SQRT_D);
      if (vis[idx]) lg = NEG_INF_F;
      logits_s[idx] = lg;
    }
    __syncthreads();

    // ---- argmax + lse (redundant per block, deterministic) ----
    {
      float v = logits_s[t]; int vi = t;
      float es = expf(v - 10.0f);
      if (t < G_ - TPB) {                       // t<128 covers 512..639
        const float v2 = logits_s[TPB + t];
        es += expf(v2 - 10.0f);
        if (v2 > v) { v = v2; vi = TPB + t; }   // larger index: strictly-greater only
      }
#pragma unroll
      for (int off = 32; off; off >>= 1) {
        const float ov = __shfl_down(v, off);
        const int oi = __shfl_down(vi, off);
        const float oe = __shfl_down(es, off);
        es += oe;
        if (ov > v || (ov == v && oi < vi)) { v = ov; vi = oi; }
      }
      if (lane == 0) { redv[wave] = v; redi[wave] = vi; reds[wave] = es; }
    }
    __syncthreads();
    if (t == 0) {
      float mv = redv[0]; int mi = redi[0]; float ss = reds[0];
      for (int w = 1; w < 8; ++w) {
        ss += reds[w];
        if (redv[w] > mv || (redv[w] == mv && redi[w] < mi)) { mv = redv[w]; mi = redi[w]; }
      }
      sel_s = mi;
      lse_s = 10.0f + logf(ss);
      vis[mi] = 1;
      if (blk == 0) out_pi[(size_t)b * T + step] = (float)mi;
    }
    __syncthreads();

    // ---- output: each block writes its g-quarter ----
    if (t < 160)
      out_logp[((size_t)b * T + step) * G_ + blk * 160 + t] =
          logits_s[blk * 160 + t] - lse_s;
  }
}

// ---------------------------------------------------------------------------
extern "C" void kernel_launch(void* const* d_in, const int* in_sizes, int n_in,
                              void* d_out, int out_size, void* d_ws, size_t ws_size,
                              hipStream_t stream)
{
  const float* emb     = (const float*)d_in[0];
  const float* W_node  = (const float*)d_in[1];
  const float* W_fixed = (const float*)d_in[2];
  const float* W_step  = (const float*)d_in[3];
  const float* W_out   = (const float*)d_in[4];
  const int*   n_steps = (const int*)d_in[5];

  float* ws = (float*)d_ws;
  float* fixed_ctx = ws;
  float* q0        = fixed_ctx + B_ * D_;
  float* Bmat      = q0 + B_ * D_;
  float* gkT       = Bmat + D_ * 1024;
  float* gv        = gkT + (size_t)B_ * D_ * G_;
  float* lk2T      = gv + (size_t)B_ * D_ * G_;
  float* q_all     = lk2T + (size_t)B_ * D_ * G_;
  float* comm1     = q_all + (size_t)B_ * G_ * D_;           // B*2*NBLK*G floats
  unsigned int* bar = (unsigned int*)(comm1 + (size_t)B_ * 2 * NBLK * G_);

  hipMemsetAsync(bar, 0, B_ * 32 * sizeof(unsigned int), stream);
  precompute_ctx<<<B_, 256, 0, stream>>>(emb, W_fixed, W_step, fixed_ctx, q0);
  build_bmat<<<D_, 256, 0, stream>>>(W_node, W_step, W_out, Bmat);
  gemm_scatter<<<dim3(320, 8), 256, 0, stream>>>(emb, Bmat, fixed_ctx,
                                                 gkT, gv, lk2T, q_all);
  step_headsplit<<<B_ * NBLK, TPB, 0, stream>>>(gkT, gv, lk2T, q_all, q0, n_steps,
                                                comm1, bar, (float*)d_out);
}

// Round 5
// 6013.181 us; speedup vs baseline: 3.1081x; 1.2092x over previous
//
#include <hip/hip_runtime.h>
#include <math.h>

#define B_ 64
#define G_ 640
#define D_ 256
#define H_ 8
#define DH_ 32
#define NBLK 4
#define TPB 512
#define GVL 512           // g's of gv kept in LDS (rest in regs)
#define GVSTR 516         // padded LDS row stride (floats)
#define NEG_INF_F (-1e9f)

__device__ __constant__ float INV_SQRT_DH = 0.17677669529663687f; // 1/sqrt(32)
__device__ __constant__ float INV_SQRT_D  = 0.0625f;              // 1/sqrt(256)

// ---------------------------------------------------------------------------
// K1: graph_embed (mean over G), fixed_ctx = ge @ W_fixed, q0 = fixed_ctx + ge @ W_step
// ---------------------------------------------------------------------------
__global__ __launch_bounds__(256) void precompute_ctx(
    const float* __restrict__ emb, const float* __restrict__ W_fixed,
    const float* __restrict__ W_step, float* __restrict__ fixed_ctx,
    float* __restrict__ q0)
{
  const int b = blockIdx.x, d = threadIdx.x;
  __shared__ float ge[D_];
  const float* eb = emb + (size_t)b * G_ * D_;
  float s = 0.f;
  for (int g = 0; g < G_; ++g) s += eb[(size_t)g * D_ + d];
  ge[d] = s * (1.0f / (float)G_);
  __syncthreads();
  float fc = 0.f, qq = 0.f;
  for (int k = 0; k < D_; ++k) {
    const float gk = ge[k];
    fc = fmaf(gk, W_fixed[k * D_ + d], fc);
    qq = fmaf(gk, W_step[k * D_ + d], qq);
  }
  fixed_ctx[b * D_ + d] = fc;
  q0[b * D_ + d] = fc + qq;
}

// ---------------------------------------------------------------------------
// K0: Bmat [256 x 1024] = [ gk | gv | Wc = W_node3 @ W_out^T | W_step ]
// ---------------------------------------------------------------------------
__global__ __launch_bounds__(256) void build_bmat(
    const float* __restrict__ W_node, const float* __restrict__ W_step,
    const float* __restrict__ W_out, float* __restrict__ Bmat)
{
  const int k = blockIdx.x, t = threadIdx.x;
  __shared__ float wn3[D_];
  wn3[t] = W_node[k * 768 + 512 + t];
  __syncthreads();
  Bmat[k * 1024 + t]       = W_node[k * 768 + t];
  Bmat[k * 1024 + 256 + t] = W_node[k * 768 + 256 + t];
  float acc = 0.f;
  for (int j = 0; j < D_; ++j) acc = fmaf(wn3[j], W_out[t * D_ + j], acc);
  Bmat[k * 1024 + 512 + t] = acc;
  Bmat[k * 1024 + 768 + t] = W_step[k * D_ + t];
}

// ---------------------------------------------------------------------------
// K2: C[40960 x 1024] = emb @ Bmat, scatter to gkT/gv/lk2T/q_all
// ---------------------------------------------------------------------------
__global__ __launch_bounds__(256) void gemm_scatter(
    const float* __restrict__ A, const float* __restrict__ Bm,
    const float* __restrict__ fixed_ctx,
    float* __restrict__ gkT, float* __restrict__ gv,
    float* __restrict__ lk2T, float* __restrict__ q_all)
{
  __shared__ float As[16][132];
  __shared__ float Bs[16][132];
  const int tid = threadIdx.x;
  const int bm = blockIdx.x;   // 320
  const int bn = blockIdx.y;   // 8
  const int tr = tid / 16, tc = tid % 16;
  const int row0 = bm * 128, col0 = bn * 128;
  float acc[8][8];
#pragma unroll
  for (int i = 0; i < 8; ++i)
#pragma unroll
    for (int j = 0; j < 8; ++j) acc[i][j] = 0.f;

  for (int k0 = 0; k0 < D_; k0 += 16) {
#pragma unroll
    for (int s = tid; s < 512; s += 256) {
      const int r = s >> 2, c4 = (s & 3) * 4;
      const float4 v = *(const float4*)&A[(size_t)(row0 + r) * D_ + k0 + c4];
      As[c4 + 0][r] = v.x; As[c4 + 1][r] = v.y;
      As[c4 + 2][r] = v.z; As[c4 + 3][r] = v.w;
    }
#pragma unroll
    for (int s = tid; s < 512; s += 256) {
      const int r = s >> 5, c4 = (s & 31) * 4;
      *(float4*)&Bs[r][c4] = *(const float4*)&Bm[(size_t)(k0 + r) * 1024 + col0 + c4];
    }
    __syncthreads();
#pragma unroll
    for (int kk = 0; kk < 16; ++kk) {
      float a[8], bfr[8];
#pragma unroll
      for (int i = 0; i < 8; ++i) a[i] = As[kk][tr * 8 + i];
#pragma unroll
      for (int j = 0; j < 8; ++j) bfr[j] = Bs[kk][tc * 8 + j];
#pragma unroll
      for (int i = 0; i < 8; ++i)
#pragma unroll
        for (int j = 0; j < 8; ++j) acc[i][j] = fmaf(a[i], bfr[j], acc[i][j]);
    }
    __syncthreads();
  }

#pragma unroll
  for (int i = 0; i < 8; ++i) {
    const int row = row0 + tr * 8 + i;
    const int bb = row / G_;
    const int g = row - bb * G_;
#pragma unroll
    for (int j = 0; j < 8; ++j) {
      const int n = col0 + tc * 8 + j;
      const float v = acc[i][j];
      if (n < 256) {
        const int h = n >> 5, d = n & 31;
        gkT[(((size_t)bb * H_ + h) * DH_ + d) * G_ + g] = v;
      } else if (n < 512) {
        const int m2 = n - 256, h = m2 >> 5, d = m2 & 31;
        gv[(((size_t)bb * H_ + h) * G_ + g) * DH_ + d] = v;
      } else if (n < 768) {
        const int d = n - 512;
        lk2T[((size_t)bb * D_ + d) * G_ + g] = v;
      } else {
        const int d = n - 768;
        q_all[((size_t)(bb * G_ + g)) * D_ + d] = v + fixed_ctx[bb * D_ + d];
      }
    }
  }
}

// ---------------------------------------------------------------------------
// K3: head-split decode with L3 mailbox (no acquire/release cache-maintenance).
// 256 blocks = 64 b x 4, 512 threads. blk0 = master (combine/argmax/output);
// blk1-3 = slaves (publish partials, poll 1-word sel mailbox).
// ---------------------------------------------------------------------------
__global__ __launch_bounds__(TPB, 2) void step_mailbox(
    const float* __restrict__ gkT, const float* __restrict__ gv,
    const float* __restrict__ lk2T, const float* __restrict__ q_all,
    const float* __restrict__ q0, const int* __restrict__ n_steps_p,
    float* __restrict__ partials,       // [B][3][G]
    unsigned int* __restrict__ flags,   // [B][8]
    unsigned int* __restrict__ selw,    // [B*32]
    float* __restrict__ out)
{
  const int x = blockIdx.x;
  const int b   = ((x >> 5) << 3) | (x & 7);   // XCD-swizzle heuristic
  const int blk = (x >> 3) & 3;
  const int t = threadIdx.x;
  const int T = *n_steps_p;
  const int h0 = blk * 2;
  const int d0 = blk * 64;
  float* out_logp = out;                         // [B][T][G]
  float* out_pi   = out + (size_t)B_ * T * G_;   // [B][T]

  // ---- LDS: ~148 KB ----
  __shared__ __align__(16) float gv_lds[2 * DH_ * GVSTR];  // 132,096 B
  __shared__ __align__(16) float attn_s[2 * G_];           // 5,120 B
  __shared__ __align__(16) float plog_l[G_];               // 2,560 B
  __shared__ float logits_s[G_];                           // 2,560 B
  __shared__ int   vis[G_];                                // 2,560 B
  __shared__ float hpart[8][64];                           // 2,048 B
  __shared__ float esum_p[8][2];
  __shared__ float heads_s[64];
  __shared__ float q_s[64];
  __shared__ float redv[8]; __shared__ int redi[8]; __shared__ float reds[8];
  __shared__ int   sel_s;
  __shared__ float lse_s;

  const int lane = t & 63, wave = t >> 6;
  const int qt  = t & 3;        // phase-2 d-quarter
  const int oct = t & 7;        // phase-4 d-octet
  const int part3 = t >> 6;     // phase-3 g-part (== wave)
  const int hd3 = t & 63;
  const int hh3 = hd3 >> 5, dd3 = hd3 & 31;

  // ---- one-time residency loads ----
  float gk_r[10][8];            // (h,g) pair p = k*128 + t/4; quarter qt
#pragma unroll
  for (int k = 0; k < 10; ++k) {
    const int p = k * 128 + (t >> 2);
    const int hh = (p >= G_) ? 1 : 0;
    const int g = p - hh * G_;
    const float* src = gkT + (((size_t)b * H_ + h0 + hh) * DH_ + qt * 8) * G_ + g;
#pragma unroll
    for (int j = 0; j < 8; ++j) gk_r[k][j] = src[(size_t)j * G_];
  }
  float lk_r[10][8];            // g = k*64 + t/8; octet oct
#pragma unroll
  for (int k = 0; k < 10; ++k) {
    const int g = k * 64 + (t >> 3);
    const float* src = lk2T + ((size_t)b * D_ + d0 + oct * 8) * G_ + g;
#pragma unroll
    for (int j = 0; j < 8; ++j) lk_r[k][j] = src[(size_t)j * G_];
  }
  for (int idx = t; idx < 2 * GVL * DH_; idx += TPB) {   // coalesced in d
    const int d = idx & 31, g = (idx >> 5) & (GVL - 1), hh = idx >> 14;
    gv_lds[(hh * DH_ + d) * GVSTR + g] =
        gv[(((size_t)b * H_ + h0 + hh) * G_ + g) * DH_ + d];
  }
  float gv_r[16];               // g in [512,640): g = 512 + part3*16 + i, (hh3,dd3)
  {
    const float* src = gv + (((size_t)b * H_ + h0 + hh3) * G_ + GVL + part3 * 16) * DH_ + dd3;
#pragma unroll
    for (int i = 0; i < 16; ++i) gv_r[i] = src[(size_t)i * DH_];
  }

  for (int idx = t; idx < G_; idx += TPB) vis[idx] = 0;
  if (t == 0) sel_s = 0;
  __syncthreads();

  unsigned int* myflags = flags + b * 8;
  unsigned int* myselw  = selw + b * 32;
  float* pb = partials + (size_t)b * 3 * G_;

  for (int step = 0; step < T; ++step) {
    // ---- phase 1: q slice (only this block's 64 components) ----
    const float* qsrc = (step == 0) ? (q0 + (size_t)b * D_)
                                    : (q_all + ((size_t)b * G_ + sel_s) * D_);
    if (t < 64) q_s[t] = qsrc[d0 + t];
    __syncthreads();

    // ---- phase 2: e[hh][g] = exp(qk/sqrt(dh)), masked -> 0 ----
    float qreg[2][8];
#pragma unroll
    for (int hh = 0; hh < 2; ++hh)
#pragma unroll
      for (int j = 0; j < 8; ++j) qreg[hh][j] = q_s[hh * 32 + qt * 8 + j];
#pragma unroll
    for (int k = 0; k < 10; ++k) {
      const int p = k * 128 + (t >> 2);
      const int hh = (p >= G_) ? 1 : 0;
      const int g = p - hh * G_;
      float a = 0.f;
#pragma unroll
      for (int j = 0; j < 8; ++j) a = fmaf(qreg[hh][j], gk_r[k][j], a);
      a += __shfl_xor(a, 1);
      a += __shfl_xor(a, 2);
      if (qt == 0) attn_s[hh * G_ + g] = vis[g] ? 0.f : expf(a * INV_SQRT_DH);
    }
    __syncthreads();

    // ---- phase 3: local heads[64] = sum_g e*gv (8 g-parts) ----
    {
      const float* gvrow = &gv_lds[(hh3 * DH_ + dd3) * GVSTR];
      const float* arow = &attn_s[hh3 * G_];
      float acc = 0.f, es = 0.f;
      const int gA = part3 * 64;
#pragma unroll
      for (int i = 0; i < 16; ++i) {
        const float4 ev = *(const float4*)&arow[gA + i * 4];
        const float4 gvv = *(const float4*)&gvrow[gA + i * 4];
        acc = fmaf(ev.x, gvv.x, acc); acc = fmaf(ev.y, gvv.y, acc);
        acc = fmaf(ev.z, gvv.z, acc); acc = fmaf(ev.w, gvv.w, acc);
        if (dd3 == 0) es += ev.x + ev.y + ev.z + ev.w;
      }
      const int gB = GVL + part3 * 16;
#pragma unroll
      for (int i = 0; i < 16; ++i) {
        const float e = arow[gB + i];
        acc = fmaf(e, gv_r[i], acc);
        if (dd3 == 0) es += e;
      }
      hpart[part3][hd3] = acc;
      if (dd3 == 0) esum_p[part3][hh3] = es;
    }
    __syncthreads();
    if (t < 64) {
      float num = 0.f, den = 0.f;
#pragma unroll
      for (int p = 0; p < 8; ++p) num += hpart[p][t];
#pragma unroll
      for (int p = 0; p < 8; ++p) den += esum_p[p][t >> 5];
      heads_s[t] = num / den;
    }
    __syncthreads();

    // ---- phase 4: partial logits over local 64 d's, all g ----
    float hreg[8];
#pragma unroll
    for (int j = 0; j < 8; ++j) hreg[j] = heads_s[oct * 8 + j];
#pragma unroll
    for (int k = 0; k < 10; ++k) {
      float a = 0.f;
#pragma unroll
      for (int j = 0; j < 8; ++j) a = fmaf(hreg[j], lk_r[k][j], a);
      a += __shfl_xor(a, 1);
      a += __shfl_xor(a, 2);
      a += __shfl_xor(a, 4);
      if (oct == 0) plog_l[k * 64 + (t >> 3)] = a;
    }
    __syncthreads();

    if (blk != 0) {
      // ================= SLAVE =================
      float* myp = pb + (size_t)(blk - 1) * G_;
      for (int idx = t; idx < G_; idx += TPB)
        __hip_atomic_store(&myp[idx], plog_l[idx], __ATOMIC_RELAXED,
                           __HIP_MEMORY_SCOPE_SYSTEM);
      __syncthreads();   // vmcnt drain: partials at L3 before flag
      if (t == 0) {
        __hip_atomic_store(&myflags[blk], (unsigned)(step + 1), __ATOMIC_RELAXED,
                           __HIP_MEMORY_SCOPE_SYSTEM);
        const unsigned tgt = (unsigned)(step + 1) << 10;
        unsigned w;
        while ((w = __hip_atomic_load(&myselw[0], __ATOMIC_RELAXED,
                                      __HIP_MEMORY_SCOPE_SYSTEM)) < tgt)
          __builtin_amdgcn_s_sleep(1);
        const int mi = (int)(w & 1023u);
        sel_s = mi;
        vis[mi] = 1;
      }
      __syncthreads();
    } else {
      // ================= MASTER =================
      if (t == 0) {
        const unsigned tg = (unsigned)(step + 1);
        for (;;) {
          const unsigned f1 = __hip_atomic_load(&myflags[1], __ATOMIC_RELAXED,
                                                __HIP_MEMORY_SCOPE_SYSTEM);
          const unsigned f2 = __hip_atomic_load(&myflags[2], __ATOMIC_RELAXED,
                                                __HIP_MEMORY_SCOPE_SYSTEM);
          const unsigned f3 = __hip_atomic_load(&myflags[3], __ATOMIC_RELAXED,
                                                __HIP_MEMORY_SCOPE_SYSTEM);
          if (f1 >= tg && f2 >= tg && f3 >= tg) break;
          __builtin_amdgcn_s_sleep(1);
        }
      }
      __syncthreads();

      // combine own partial (LDS) + 3 remote (L3) -> full logits
      for (int idx = t; idx < G_; idx += TPB) {
        float s = plog_l[idx];
        s += __hip_atomic_load(&pb[idx], __ATOMIC_RELAXED, __HIP_MEMORY_SCOPE_SYSTEM);
        s += __hip_atomic_load(&pb[G_ + idx], __ATOMIC_RELAXED, __HIP_MEMORY_SCOPE_SYSTEM);
        s += __hip_atomic_load(&pb[2 * G_ + idx], __ATOMIC_RELAXED, __HIP_MEMORY_SCOPE_SYSTEM);
        float lg = 10.0f * tanhf(s * INV_SQRT_D);
        if (vis[idx]) lg = NEG_INF_F;
        logits_s[idx] = lg;
      }
      __syncthreads();

      // argmax + lse
      {
        float v = logits_s[t]; int vi = t;
        float es = expf(v - 10.0f);
        if (t < G_ - TPB) {                      // t<128 covers 512..639
          const float v2 = logits_s[TPB + t];
          es += expf(v2 - 10.0f);
          if (v2 > v) { v = v2; vi = TPB + t; }
        }
#pragma unroll
        for (int off = 32; off; off >>= 1) {
          const float ov = __shfl_down(v, off);
          const int oi = __shfl_down(vi, off);
          const float oe = __shfl_down(es, off);
          es += oe;
          if (ov > v || (ov == v && oi < vi)) { v = ov; vi = oi; }
        }
        if (lane == 0) { redv[wave] = v; redi[wave] = vi; reds[wave] = es; }
      }
      __syncthreads();
      if (t == 0) {
        float mv = redv[0]; int mi = redi[0]; float ss = reds[0];
        for (int w = 1; w < 8; ++w) {
          ss += reds[w];
          if (redv[w] > mv || (redv[w] == mv && redi[w] < mi)) { mv = redv[w]; mi = redi[w]; }
        }
        sel_s = mi;
        // publish selection FIRST so slaves restart ASAP
        __hip_atomic_store(&myselw[0], ((unsigned)(step + 1) << 10) | (unsigned)mi,
                           __ATOMIC_RELAXED, __HIP_MEMORY_SCOPE_SYSTEM);
        lse_s = 10.0f + logf(ss);
        vis[mi] = 1;
        __builtin_nontemporal_store((float)mi, &out_pi[(size_t)b * T + step]);
      }
      __syncthreads();

      // master writes all outputs (nontemporal: keep L2 clean)
      {
        const float ls = lse_s;
        float* orow = out_logp + ((size_t)b * T + step) * G_;
        for (int idx = t; idx < G_; idx += TPB)
          __builtin_nontemporal_store(logits_s[idx] - ls, &orow[idx]);
      }
    }
  }
}

// ---------------------------------------------------------------------------
extern "C" void kernel_launch(void* const* d_in, const int* in_sizes, int n_in,
                              void* d_out, int out_size, void* d_ws, size_t ws_size,
                              hipStream_t stream)
{
  const float* emb     = (const float*)d_in[0];
  const float* W_node  = (const float*)d_in[1];
  const float* W_fixed = (const float*)d_in[2];
  const float* W_step  = (const float*)d_in[3];
  const float* W_out   = (const float*)d_in[4];
  const int*   n_steps = (const int*)d_in[5];

  float* ws = (float*)d_ws;
  float* fixed_ctx = ws;
  float* q0        = fixed_ctx + B_ * D_;
  float* Bmat      = q0 + B_ * D_;
  float* gkT       = Bmat + D_ * 1024;
  float* gv        = gkT + (size_t)B_ * D_ * G_;
  float* lk2T      = gv + (size_t)B_ * D_ * G_;
  float* q_all     = lk2T + (size_t)B_ * D_ * G_;
  float* partials  = q_all + (size_t)B_ * G_ * D_;           // B*3*G floats
  unsigned int* flags = (unsigned int*)(partials + (size_t)B_ * 3 * G_); // B*8
  unsigned int* selw  = flags + B_ * 8;                       // B*32

  hipMemsetAsync(flags, 0, (B_ * 8 + B_ * 32) * sizeof(unsigned int), stream);
  precompute_ctx<<<B_, 256, 0, stream>>>(emb, W_fixed, W_step, fixed_ctx, q0);
  build_bmat<<<D_, 256, 0, stream>>>(W_node, W_step, W_out, Bmat);
  gemm_scatter<<<dim3(320, 8), 256, 0, stream>>>(emb, Bmat, fixed_ctx,
                                                 gkT, gv, lk2T, q_all);
  step_mailbox<<<B_ * NBLK, TPB, 0, stream>>>(gkT, gv, lk2T, q_all, q0, n_steps,
                                              partials, flags, selw, (float*)d_out);
}